// Round 7
// baseline (182.647 us; speedup 1.0000x reference)
//
#include <hip/hip_runtime.h>
#include <math.h>

// CircleLoss fused, balanced pair-scheduled MFMA pipeline (R7).
// sim = xn @ xn^T, 2-term split-bf16: sim ~= (hiA+loA).hiB (drop A.loB ~2e-4).
// Upper-tri 128x128 tiles; panel p paired with panel 63-p (65 tiles/pair),
// 16 blocks/pair -> grid 512 = exactly 2 blocks/CU resident, 4-5 tiles each.
// A panel in REGISTERS per block (restaged once if the block straddles its
// pair's two panels). B double-buffered in LDS, staged by dedicated stage
// waves (wy 1,2) -- only they execute the per-tile vmcnt drain. Column sums
// combined across wy-waves in LDS (4x fewer col atomics); dedicated flush
// waves (wy 0) issue fire-and-forget device atomics that are never waited
// until the end-of-kernel counter protocol (R4-proven fence-free finalize).

#define NR    8192
#define DIMK  128
#define NT    64
#define NBLKS 512

typedef __attribute__((ext_vector_type(8))) short short8;
typedef __attribute__((ext_vector_type(4))) float f32x4;
typedef __attribute__((address_space(3))) uint32_t lds_u32;
typedef const __attribute__((address_space(1))) uint32_t glb_u32;

__device__ __forceinline__ unsigned short bf16_rne(float f) {
  uint32_t u = __float_as_uint(f);
  u += 0x7FFFu + ((u >> 16) & 1u);
  return (unsigned short)(u >> 16);
}

// ws: xhi bf16[NR*DIMK] (2MB) | xlo (2MB) | gP f32[NR] | gN f32[NR] | counter

__global__ __launch_bounds__(256) void normalize_split_kernel(
    const float* __restrict__ x, unsigned short* __restrict__ xhi,
    unsigned short* __restrict__ xlo, float* __restrict__ gP,
    float* __restrict__ gN, int* __restrict__ counter) {
  if (blockIdx.x < 32)      gP[blockIdx.x * 256 + threadIdx.x] = 0.f;
  else if (blockIdx.x < 64) gN[(blockIdx.x - 32) * 256 + threadIdx.x] = 0.f;
  if (blockIdx.x == 64 && threadIdx.x == 0) *counter = 0;

  const int wave = threadIdx.x >> 6;
  const int lane = threadIdx.x & 63;
  const int row  = blockIdx.x * 4 + wave;
  const float2 v = ((const float2*)(x + (size_t)row * DIMK))[lane];
  float ss = v.x * v.x + v.y * v.y;
  #pragma unroll
  for (int s = 1; s < 64; s <<= 1) ss += __shfl_xor(ss, s);
  const float r = rsqrtf(ss);
  const float a = v.x * r, b = v.y * r;
  const unsigned short ha = bf16_rne(a), hb = bf16_rne(b);
  const float haf = __uint_as_float((uint32_t)ha << 16);
  const float hbf = __uint_as_float((uint32_t)hb << 16);
  ushort2 hi, lo;
  hi.x = ha; hi.y = hb;
  lo.x = bf16_rne(a - haf); lo.y = bf16_rne(b - hbf);
  ((ushort2*)xhi)[(size_t)row * 64 + lane] = hi;
  ((ushort2*)xlo)[(size_t)row * 64 + lane] = lo;
}

__global__ __launch_bounds__(512, 4) void simloss_kernel(
    const unsigned short* __restrict__ xhi, const unsigned short* __restrict__ xlo,
    const int* __restrict__ tgt, float* __restrict__ gP, float* __restrict__ gN,
    int* __restrict__ counter, float* __restrict__ out) {
  __shared__ unsigned short S[32768];      // 64KB: A stage (hi|lo), then B dbuf
  __shared__ float colbuf[2][4][128][2];   // 8KB, double-buffered col partials
  __shared__ int tAs[2][128];
  __shared__ int tBs[5][128];
  __shared__ float red[512];
  __shared__ int islast;

  const int tid  = threadIdx.x;
  const int wave = tid >> 6, lane = tid & 63;
  const int wy = wave & 3, wx = wave >> 2;   // frag grid: 4 row-waves x 2 col-waves
  const int q = lane >> 4, mcol = lane & 15;
  const bool isStage = (wy == 1) || (wy == 2);
  const bool isFlush = (wy == 0);
  const int srank = (wy - 1) + wx * 2;       // 0..3 for stage waves

  const int p  = blockIdx.x >> 4;            // pair index (0..31)
  const int b  = blockIdx.x & 15;
  const int n1 = NT - p;                     // tiles in panel1 (bi=p)
  const int t0 = (b * (NT + 1)) >> 4;        // 65 tiles per pair
  const int t1 = ((b + 1) * (NT + 1)) >> 4;
  const int ntile = t1 - t0;
  const int p2 = NT - 1 - p;                 // panel2 bi

  int cur_bi = (t0 < n1) ? p : p2;

  // ---- prologue: targets ----
  if (tid < 128)       tAs[0][tid] = tgt[cur_bi * 128 + tid];
  else if (tid < 256)  tAs[1][tid - 128] = tgt[p2 * 128 + (tid - 128)];
  for (int v = tid; v < ntile * 128; v += 512) {
    const int ix = t0 + (v >> 7);
    const int bj = (ix < n1) ? p + ix : p2 + (ix - n1);
    tBs[v >> 7][v & 127] = tgt[bj * 128 + (v & 127)];
  }

  // ---- A staging (all waves). hi -> S[0..16K), lo -> S[16K..32K) ushorts ----
  auto stageA = [&](int bi) {
    const unsigned short* gh = xhi + (size_t)bi * 128 * DIMK;
    const unsigned short* gl = xlo + (size_t)bi * 128 * DIMK;
    #pragma unroll
    for (int g = 0; g < 4; ++g) {
      const int r  = wave * 16 + g * 4 + (lane >> 4);
      const int sc = (lane & 15) ^ (r & 15);   // XOR swizzle (R6-proven)
      __builtin_amdgcn_global_load_lds((glb_u32*)(gh + (size_t)r * DIMK + sc * 8),
          (lds_u32*)&S[(wave * 16 + g * 4) * 128], 16, 0, 0);
      __builtin_amdgcn_global_load_lds((glb_u32*)(gl + (size_t)r * DIMK + sc * 8),
          (lds_u32*)&S[16384 + (wave * 16 + g * 4) * 128], 16, 0, 0);
    }
  };
  // ---- B staging (stage waves only), 8 instrs each, 32KB tile ----
  auto stageB = [&](int bj, int buf) {
    const unsigned short* gb = xhi + (size_t)bj * 128 * DIMK;
    unsigned short* dst = &S[buf * 16384];
    #pragma unroll
    for (int g = 0; g < 8; ++g) {
      const int r  = srank * 32 + g * 4 + (lane >> 4);
      const int sc = (lane & 15) ^ (r & 15);
      __builtin_amdgcn_global_load_lds((glb_u32*)(gb + (size_t)r * DIMK + sc * 8),
          (lds_u32*)&dst[(srank * 32 + g * 4) * 128], 16, 0, 0);
    }
  };

  short8 Ah[2][4], Al[2][4];
  int ta[2][4];
  auto extractA = [&](int seg) {
    #pragma unroll
    for (int fr = 0; fr < 2; ++fr) {
      const int r = wy * 32 + fr * 16 + mcol;
      #pragma unroll
      for (int ks = 0; ks < 4; ++ks) {
        const int pc = (ks * 4 + q) ^ mcol;
        Ah[fr][ks] = *(const short8*)&S[r * 128 + pc * 8];
        Al[fr][ks] = *(const short8*)&S[16384 + r * 128 + pc * 8];
      }
    }
    #pragma unroll
    for (int fr = 0; fr < 2; ++fr)
      #pragma unroll
      for (int rg = 0; rg < 4; ++rg)
        ta[fr][rg] = tAs[seg][wy * 32 + fr * 16 + q * 4 + rg];
  };

  float rowP[2][4] = {{0.f}}, rowN[2][4] = {{0.f}};
  auto flushRows = [&](int bi) {
    #pragma unroll
    for (int fr = 0; fr < 2; ++fr)
      #pragma unroll
      for (int rg = 0; rg < 4; ++rg) {
        float vp = rowP[fr][rg], vn = rowN[fr][rg];
        #pragma unroll
        for (int m = 1; m < 16; m <<= 1) {
          vp += __shfl_xor(vp, m);
          vn += __shfl_xor(vn, m);
        }
        if (mcol == 0) {
          const int row = bi * 128 + wy * 32 + fr * 16 + q * 4 + rg;
          atomicAdd(&gP[row], vp);
          atomicAdd(&gN[row], vn);
        }
      }
  };

  stageA(cur_bi);
  __syncthreads();            // A staged + tAs/tBs visible
  extractA(0);
  __builtin_amdgcn_s_waitcnt(49279);   // lgkm0: all frag reads done
  __builtin_amdgcn_s_barrier();        // -> S reusable as B buffers
  if (isStage) stageB((t0 < n1) ? p + t0 : p2 + (t0 - n1), 0);

  for (int tl = 0; tl < ntile; ++tl) {
    const int ix = t0 + tl;
    const int bi = (ix < n1) ? p : p2;
    const int bj = (ix < n1) ? p + ix : p2 + (ix - n1);

    if (bi != cur_bi) {       // panel switch (at most once per block)
      flushRows(cur_bi);
      cur_bi = bi;
      stageA(cur_bi);         // overwrites both B buffers (none pending)
      __syncthreads();
      extractA(1);
      #pragma unroll
      for (int fr = 0; fr < 2; ++fr)
        #pragma unroll
        for (int rg = 0; rg < 4; ++rg) { rowP[fr][rg] = 0.f; rowN[fr][rg] = 0.f; }
      __builtin_amdgcn_s_waitcnt(49279);
      __builtin_amdgcn_s_barrier();
      if (isStage) stageB(bj, tl & 1);
    }

    // start barrier: only stage waves drain their B loads (vm0+lgkm0 = 112)
    if (isStage) __builtin_amdgcn_s_waitcnt(112);
    __builtin_amdgcn_s_barrier();

    // prefetch next tile's B (same panel only; cross-panel handled above)
    if (tl + 1 < ntile) {
      const int ix2 = ix + 1;
      if ((ix2 < n1) == (ix < n1)) {
        const int bj2 = (ix2 < n1) ? p + ix2 : p2 + (ix2 - n1);
        if (isStage) stageB(bj2, (tl + 1) & 1);
      }
    }

    // ---- compute tile ----
    const unsigned short* Bb = &S[(tl & 1) * 16384];
    f32x4 acc[2][4];
    #pragma unroll
    for (int fr = 0; fr < 2; ++fr)
      #pragma unroll
      for (int fc = 0; fc < 4; ++fc)
        acc[fr][fc] = (f32x4){0.f, 0.f, 0.f, 0.f};
    #pragma unroll
    for (int ks = 0; ks < 4; ++ks) {
      short8 bh[4];
      #pragma unroll
      for (int fc = 0; fc < 4; ++fc) {
        const int rb = wx * 64 + fc * 16 + mcol;
        const int pc = (ks * 4 + q) ^ mcol;
        bh[fc] = *(const short8*)&Bb[rb * 128 + pc * 8];
      }
      #pragma unroll
      for (int fc = 0; fc < 4; ++fc) {
        acc[0][fc] = __builtin_amdgcn_mfma_f32_16x16x32_bf16(Ah[0][ks], bh[fc], acc[0][fc], 0, 0, 0);
        acc[1][fc] = __builtin_amdgcn_mfma_f32_16x16x32_bf16(Ah[1][ks], bh[fc], acc[1][fc], 0, 0, 0);
        acc[0][fc] = __builtin_amdgcn_mfma_f32_16x16x32_bf16(Al[0][ks], bh[fc], acc[0][fc], 0, 0, 0);
        acc[1][fc] = __builtin_amdgcn_mfma_f32_16x16x32_bf16(Al[1][ks], bh[fc], acc[1][fc], 0, 0, 0);
      }
    }

    // ---- epilogue: C layout col = mcol, row = q*4 + reg ----
    int tb[4];
    #pragma unroll
    for (int fc = 0; fc < 4; ++fc) tb[fc] = tBs[tl][wx * 64 + fc * 16 + mcol];
    float cP[4] = {0.f, 0.f, 0.f, 0.f}, cN[4] = {0.f, 0.f, 0.f, 0.f};
    #pragma unroll
    for (int fr = 0; fr < 2; ++fr) {
      #pragma unroll
      for (int rg = 0; rg < 4; ++rg) {
        const int taa = ta[fr][rg];
        float vp = 0.f, vn = 0.f;
        #pragma unroll
        for (int fc = 0; fc < 4; ++fc) {
          const float s  = acc[fr][fc][rg];
          const bool pos = (taa == tb[fc]);
          const float ap = fmaxf(1.25f - s, 0.f);
          const float an = fmaxf(s - 0.25f, 0.f);
          const float arg = pos ? ap * fmaf(s, 64.f, -48.f) : an * an * 64.f;
          const float e = __expf(arg);
          const float ep = pos ? e : 0.f;
          const float en = pos ? 0.f : e;
          vp += ep; vn += en;
          cP[fc] += ep; cN[fc] += en;
        }
        rowP[fr][rg] += vp;
        rowN[fr][rg] += vn;
      }
    }

    // col partials: q-reduce then ds_write (16 lanes per wave)
    #pragma unroll
    for (int fc = 0; fc < 4; ++fc) {
      cP[fc] += __shfl_xor(cP[fc], 16); cP[fc] += __shfl_xor(cP[fc], 32);
      cN[fc] += __shfl_xor(cN[fc], 16); cN[fc] += __shfl_xor(cN[fc], 32);
    }
    if (q == 0) {
      #pragma unroll
      for (int fc = 0; fc < 4; ++fc) {
        float2 v; v.x = cP[fc]; v.y = cN[fc];
        *(float2*)&colbuf[tl & 1][wy][wx * 64 + fc * 16 + mcol][0] = v;
      }
    }
    __builtin_amdgcn_s_waitcnt(49279);   // lgkm0: colbuf writes visible
    __builtin_amdgcn_s_barrier();

    // flush waves: combine 4 wy slices, fire-and-forget device atomics
    if (isFlush && bj != bi) {
      const int col = wx * 64 + lane;
      float sp = 0.f, sn = 0.f;
      #pragma unroll
      for (int w = 0; w < 4; ++w) {
        const float2 v = *(const float2*)&colbuf[tl & 1][w][col][0];
        sp += v.x; sn += v.y;
      }
      atomicAdd(&gP[bj * 128 + col], sp);
      atomicAdd(&gN[bj * 128 + col], sn);
    }
  }
  flushRows(cur_bi);

  // ---- fence-free last-block finalize (R4-proven) ----
  __builtin_amdgcn_s_waitcnt(0);   // all my atomics ack'd before counter bump
  __syncthreads();
  if (tid == 0) islast = (atomicAdd(counter, 1) == NBLKS - 1) ? 1 : 0;
  __syncthreads();
  if (islast) {
    float local = 0.f;
    #pragma unroll 1
    for (int bb = 0; bb < 2; ++bb) {
      const int base = bb * 4096 + tid * 8;
      float pv[8], nv[8];
      #pragma unroll
      for (int u = 0; u < 8; ++u) pv[u] = atomicAdd(&gP[base + u], 0.0f);
      #pragma unroll
      for (int u = 0; u < 8; ++u) nv[u] = atomicAdd(&gN[base + u], 0.0f);
      #pragma unroll
      for (int u = 0; u < 8; ++u) local += log1pf(pv[u] * nv[u]);
    }
    red[tid] = local;
    __syncthreads();
    for (int s2 = 256; s2 > 0; s2 >>= 1) {
      if (tid < s2) red[tid] += red[tid + s2];
      __syncthreads();
    }
    if (tid == 0) out[0] = red[0] / (float)NR;
  }
}

extern "C" void kernel_launch(void* const* d_in, const int* in_sizes, int n_in,
                              void* d_out, int out_size, void* d_ws, size_t ws_size,
                              hipStream_t stream) {
  const float* x  = (const float*)d_in[0];
  const int* tgt  = (const int*)d_in[1];
  float* out      = (float*)d_out;

  unsigned short* xhi = (unsigned short*)d_ws;
  unsigned short* xlo = xhi + (size_t)NR * DIMK;
  float* gP = (float*)((char*)d_ws + (size_t)NR * DIMK * 4);
  float* gN = gP + NR;
  int* counter = (int*)(gN + NR);

  normalize_split_kernel<<<NR / 4, 256, 0, stream>>>(x, xhi, xlo, gP, gN, counter);
  simloss_kernel<<<NBLKS, 512, 0, stream>>>(xhi, xlo, tgt, gP, gN, counter, out);
}

// Round 8
// 121.434 us; speedup vs baseline: 1.5041x; 1.5041x over previous
//
#include <hip/hip_runtime.h>
#include <math.h>

// CircleLoss fused, balanced pair-scheduled MFMA pipeline (R8 = R7 with the
// spill fixed: __launch_bounds__(512,2) -- R7's (512,4) forced VGPR<=64 and
// spilled all A-fragments/accumulators to scratch (187MB FETCH / 160MB WRITE
// of pure spill traffic). R6 proved (512,2) holds this register plan at ~100
// VGPR with no spill; LDS 78KB still fits 2 blocks/CU.)
// sim = xn @ xn^T, 2-term split-bf16: sim ~= (hiA+loA).hiB (drop A.loB ~2e-4).
// Upper-tri 128x128 tiles; panel p paired with panel 63-p (65 tiles/pair),
// 16 blocks/pair -> grid 512 = exactly 2 blocks/CU resident, 4-5 tiles each.
// A panel in REGISTERS per block; B double-buffered in LDS, staged by stage
// waves (wy 1,2) -- only they execute the per-tile vmcnt drain. Column sums
// combined across wy-waves in LDS (4x fewer col atomics); flush waves (wy 0)
// issue fire-and-forget device atomics, waited only once at kernel end
// (R4-proven fence-free counter finalize).

#define NR    8192
#define DIMK  128
#define NT    64
#define NBLKS 512

typedef __attribute__((ext_vector_type(8))) short short8;
typedef __attribute__((ext_vector_type(4))) float f32x4;
typedef __attribute__((address_space(3))) uint32_t lds_u32;
typedef const __attribute__((address_space(1))) uint32_t glb_u32;

__device__ __forceinline__ unsigned short bf16_rne(float f) {
  uint32_t u = __float_as_uint(f);
  u += 0x7FFFu + ((u >> 16) & 1u);
  return (unsigned short)(u >> 16);
}

// ws: xhi bf16[NR*DIMK] (2MB) | xlo (2MB) | gP f32[NR] | gN f32[NR] | counter

__global__ __launch_bounds__(256) void normalize_split_kernel(
    const float* __restrict__ x, unsigned short* __restrict__ xhi,
    unsigned short* __restrict__ xlo, float* __restrict__ gP,
    float* __restrict__ gN, int* __restrict__ counter) {
  if (blockIdx.x < 32)      gP[blockIdx.x * 256 + threadIdx.x] = 0.f;
  else if (blockIdx.x < 64) gN[(blockIdx.x - 32) * 256 + threadIdx.x] = 0.f;
  if (blockIdx.x == 64 && threadIdx.x == 0) *counter = 0;

  const int wave = threadIdx.x >> 6;
  const int lane = threadIdx.x & 63;
  const int row  = blockIdx.x * 4 + wave;
  const float2 v = ((const float2*)(x + (size_t)row * DIMK))[lane];
  float ss = v.x * v.x + v.y * v.y;
  #pragma unroll
  for (int s = 1; s < 64; s <<= 1) ss += __shfl_xor(ss, s);
  const float r = rsqrtf(ss);
  const float a = v.x * r, b = v.y * r;
  const unsigned short ha = bf16_rne(a), hb = bf16_rne(b);
  const float haf = __uint_as_float((uint32_t)ha << 16);
  const float hbf = __uint_as_float((uint32_t)hb << 16);
  ushort2 hi, lo;
  hi.x = ha; hi.y = hb;
  lo.x = bf16_rne(a - haf); lo.y = bf16_rne(b - hbf);
  ((ushort2*)xhi)[(size_t)row * 64 + lane] = hi;
  ((ushort2*)xlo)[(size_t)row * 64 + lane] = lo;
}

__global__ __launch_bounds__(512, 2) void simloss_kernel(
    const unsigned short* __restrict__ xhi, const unsigned short* __restrict__ xlo,
    const int* __restrict__ tgt, float* __restrict__ gP, float* __restrict__ gN,
    int* __restrict__ counter, float* __restrict__ out) {
  __shared__ unsigned short S[32768];      // 64KB: A stage (hi|lo), then B dbuf
  __shared__ float colbuf[2][4][128][2];   // 8KB, double-buffered col partials
  __shared__ int tAs[2][128];
  __shared__ int tBs[5][128];
  __shared__ float red[512];
  __shared__ int islast;

  const int tid  = threadIdx.x;
  const int wave = tid >> 6, lane = tid & 63;
  const int wy = wave & 3, wx = wave >> 2;   // frag grid: 4 row-waves x 2 col-waves
  const int q = lane >> 4, mcol = lane & 15;
  const bool isStage = (wy == 1) || (wy == 2);
  const bool isFlush = (wy == 0);
  const int srank = (wy - 1) + wx * 2;       // 0..3 for stage waves

  const int p  = blockIdx.x >> 4;            // pair index (0..31)
  const int b  = blockIdx.x & 15;
  const int n1 = NT - p;                     // tiles in panel1 (bi=p)
  const int t0 = (b * (NT + 1)) >> 4;        // 65 tiles per pair
  const int t1 = ((b + 1) * (NT + 1)) >> 4;
  const int ntile = t1 - t0;
  const int p2 = NT - 1 - p;                 // panel2 bi

  int cur_bi = (t0 < n1) ? p : p2;

  // ---- prologue: targets ----
  if (tid < 128)       tAs[0][tid] = tgt[cur_bi * 128 + tid];
  else if (tid < 256)  tAs[1][tid - 128] = tgt[p2 * 128 + (tid - 128)];
  for (int v = tid; v < ntile * 128; v += 512) {
    const int ix = t0 + (v >> 7);
    const int bj = (ix < n1) ? p + ix : p2 + (ix - n1);
    tBs[v >> 7][v & 127] = tgt[bj * 128 + (v & 127)];
  }

  // ---- A staging (all waves). hi -> S[0..16K), lo -> S[16K..32K) ushorts ----
  auto stageA = [&](int bi) {
    const unsigned short* gh = xhi + (size_t)bi * 128 * DIMK;
    const unsigned short* gl = xlo + (size_t)bi * 128 * DIMK;
    #pragma unroll
    for (int g = 0; g < 4; ++g) {
      const int r  = wave * 16 + g * 4 + (lane >> 4);
      const int sc = (lane & 15) ^ (r & 15);   // XOR swizzle (R6-proven)
      __builtin_amdgcn_global_load_lds((glb_u32*)(gh + (size_t)r * DIMK + sc * 8),
          (lds_u32*)&S[(wave * 16 + g * 4) * 128], 16, 0, 0);
      __builtin_amdgcn_global_load_lds((glb_u32*)(gl + (size_t)r * DIMK + sc * 8),
          (lds_u32*)&S[16384 + (wave * 16 + g * 4) * 128], 16, 0, 0);
    }
  };
  // ---- B staging (stage waves only), 8 instrs each, 32KB tile ----
  auto stageB = [&](int bj, int buf) {
    const unsigned short* gb = xhi + (size_t)bj * 128 * DIMK;
    unsigned short* dst = &S[buf * 16384];
    #pragma unroll
    for (int g = 0; g < 8; ++g) {
      const int r  = srank * 32 + g * 4 + (lane >> 4);
      const int sc = (lane & 15) ^ (r & 15);
      __builtin_amdgcn_global_load_lds((glb_u32*)(gb + (size_t)r * DIMK + sc * 8),
          (lds_u32*)&dst[(srank * 32 + g * 4) * 128], 16, 0, 0);
    }
  };

  short8 Ah[2][4], Al[2][4];
  int ta[2][4];
  auto extractA = [&](int seg) {
    #pragma unroll
    for (int fr = 0; fr < 2; ++fr) {
      const int r = wy * 32 + fr * 16 + mcol;
      #pragma unroll
      for (int ks = 0; ks < 4; ++ks) {
        const int pc = (ks * 4 + q) ^ mcol;
        Ah[fr][ks] = *(const short8*)&S[r * 128 + pc * 8];
        Al[fr][ks] = *(const short8*)&S[16384 + r * 128 + pc * 8];
      }
    }
    #pragma unroll
    for (int fr = 0; fr < 2; ++fr)
      #pragma unroll
      for (int rg = 0; rg < 4; ++rg)
        ta[fr][rg] = tAs[seg][wy * 32 + fr * 16 + q * 4 + rg];
  };

  float rowP[2][4] = {{0.f}}, rowN[2][4] = {{0.f}};
  auto flushRows = [&](int bi) {
    #pragma unroll
    for (int fr = 0; fr < 2; ++fr)
      #pragma unroll
      for (int rg = 0; rg < 4; ++rg) {
        float vp = rowP[fr][rg], vn = rowN[fr][rg];
        #pragma unroll
        for (int m = 1; m < 16; m <<= 1) {
          vp += __shfl_xor(vp, m);
          vn += __shfl_xor(vn, m);
        }
        if (mcol == 0) {
          const int row = bi * 128 + wy * 32 + fr * 16 + q * 4 + rg;
          atomicAdd(&gP[row], vp);
          atomicAdd(&gN[row], vn);
        }
      }
  };

  stageA(cur_bi);
  __syncthreads();            // A staged + tAs/tBs visible
  extractA(0);
  __builtin_amdgcn_s_waitcnt(49279);   // lgkm0: all frag reads done
  __builtin_amdgcn_s_barrier();        // -> S reusable as B buffers
  if (isStage) stageB((t0 < n1) ? p + t0 : p2 + (t0 - n1), 0);

  for (int tl = 0; tl < ntile; ++tl) {
    const int ix = t0 + tl;
    const int bi = (ix < n1) ? p : p2;
    const int bj = (ix < n1) ? p + ix : p2 + (ix - n1);

    if (bi != cur_bi) {       // panel switch (at most once per block)
      flushRows(cur_bi);
      cur_bi = bi;
      stageA(cur_bi);         // overwrites both B buffers (none pending)
      __syncthreads();
      extractA(1);
      #pragma unroll
      for (int fr = 0; fr < 2; ++fr)
        #pragma unroll
        for (int rg = 0; rg < 4; ++rg) { rowP[fr][rg] = 0.f; rowN[fr][rg] = 0.f; }
      __builtin_amdgcn_s_waitcnt(49279);
      __builtin_amdgcn_s_barrier();
      if (isStage) stageB(bj, tl & 1);
    }

    // start barrier: only stage waves drain their B loads (vm0+lgkm0 = 112)
    if (isStage) __builtin_amdgcn_s_waitcnt(112);
    __builtin_amdgcn_s_barrier();

    // prefetch next tile's B (same panel only; cross-panel handled above)
    if (tl + 1 < ntile) {
      const int ix2 = ix + 1;
      if ((ix2 < n1) == (ix < n1)) {
        const int bj2 = (ix2 < n1) ? p + ix2 : p2 + (ix2 - n1);
        if (isStage) stageB(bj2, (tl + 1) & 1);
      }
    }

    // ---- compute tile ----
    const unsigned short* Bb = &S[(tl & 1) * 16384];
    f32x4 acc[2][4];
    #pragma unroll
    for (int fr = 0; fr < 2; ++fr)
      #pragma unroll
      for (int fc = 0; fc < 4; ++fc)
        acc[fr][fc] = (f32x4){0.f, 0.f, 0.f, 0.f};
    #pragma unroll
    for (int ks = 0; ks < 4; ++ks) {
      short8 bh[4];
      #pragma unroll
      for (int fc = 0; fc < 4; ++fc) {
        const int rb = wx * 64 + fc * 16 + mcol;
        const int pc = (ks * 4 + q) ^ mcol;
        bh[fc] = *(const short8*)&Bb[rb * 128 + pc * 8];
      }
      #pragma unroll
      for (int fc = 0; fc < 4; ++fc) {
        acc[0][fc] = __builtin_amdgcn_mfma_f32_16x16x32_bf16(Ah[0][ks], bh[fc], acc[0][fc], 0, 0, 0);
        acc[1][fc] = __builtin_amdgcn_mfma_f32_16x16x32_bf16(Ah[1][ks], bh[fc], acc[1][fc], 0, 0, 0);
        acc[0][fc] = __builtin_amdgcn_mfma_f32_16x16x32_bf16(Al[0][ks], bh[fc], acc[0][fc], 0, 0, 0);
        acc[1][fc] = __builtin_amdgcn_mfma_f32_16x16x32_bf16(Al[1][ks], bh[fc], acc[1][fc], 0, 0, 0);
      }
    }

    // ---- epilogue: C layout col = mcol, row = q*4 + reg ----
    int tb[4];
    #pragma unroll
    for (int fc = 0; fc < 4; ++fc) tb[fc] = tBs[tl][wx * 64 + fc * 16 + mcol];
    float cP[4] = {0.f, 0.f, 0.f, 0.f}, cN[4] = {0.f, 0.f, 0.f, 0.f};
    #pragma unroll
    for (int fr = 0; fr < 2; ++fr) {
      #pragma unroll
      for (int rg = 0; rg < 4; ++rg) {
        const int taa = ta[fr][rg];
        float vp = 0.f, vn = 0.f;
        #pragma unroll
        for (int fc = 0; fc < 4; ++fc) {
          const float s  = acc[fr][fc][rg];
          const bool pos = (taa == tb[fc]);
          const float ap = fmaxf(1.25f - s, 0.f);
          const float an = fmaxf(s - 0.25f, 0.f);
          const float arg = pos ? ap * fmaf(s, 64.f, -48.f) : an * an * 64.f;
          const float e = __expf(arg);
          const float ep = pos ? e : 0.f;
          const float en = pos ? 0.f : e;
          vp += ep; vn += en;
          cP[fc] += ep; cN[fc] += en;
        }
        rowP[fr][rg] += vp;
        rowN[fr][rg] += vn;
      }
    }

    // col partials: q-reduce then ds_write (16 lanes per wave)
    #pragma unroll
    for (int fc = 0; fc < 4; ++fc) {
      cP[fc] += __shfl_xor(cP[fc], 16); cP[fc] += __shfl_xor(cP[fc], 32);
      cN[fc] += __shfl_xor(cN[fc], 16); cN[fc] += __shfl_xor(cN[fc], 32);
    }
    if (q == 0) {
      #pragma unroll
      for (int fc = 0; fc < 4; ++fc) {
        float2 v; v.x = cP[fc]; v.y = cN[fc];
        *(float2*)&colbuf[tl & 1][wy][wx * 64 + fc * 16 + mcol][0] = v;
      }
    }
    __builtin_amdgcn_s_waitcnt(49279);   // lgkm0: colbuf writes visible
    __builtin_amdgcn_s_barrier();

    // flush waves: combine 4 wy slices, fire-and-forget device atomics
    if (isFlush && bj != bi) {
      const int col = wx * 64 + lane;
      float sp = 0.f, sn = 0.f;
      #pragma unroll
      for (int w = 0; w < 4; ++w) {
        const float2 v = *(const float2*)&colbuf[tl & 1][w][col][0];
        sp += v.x; sn += v.y;
      }
      atomicAdd(&gP[bj * 128 + col], sp);
      atomicAdd(&gN[bj * 128 + col], sn);
    }
  }
  flushRows(cur_bi);

  // ---- fence-free last-block finalize (R4-proven) ----
  __builtin_amdgcn_s_waitcnt(0);   // all my atomics ack'd before counter bump
  __syncthreads();
  if (tid == 0) islast = (atomicAdd(counter, 1) == NBLKS - 1) ? 1 : 0;
  __syncthreads();
  if (islast) {
    float local = 0.f;
    #pragma unroll 1
    for (int bb = 0; bb < 2; ++bb) {
      const int base = bb * 4096 + tid * 8;
      float pv[8], nv[8];
      #pragma unroll
      for (int u = 0; u < 8; ++u) pv[u] = atomicAdd(&gP[base + u], 0.0f);
      #pragma unroll
      for (int u = 0; u < 8; ++u) nv[u] = atomicAdd(&gN[base + u], 0.0f);
      #pragma unroll
      for (int u = 0; u < 8; ++u) local += log1pf(pv[u] * nv[u]);
    }
    red[tid] = local;
    __syncthreads();
    for (int s2 = 256; s2 > 0; s2 >>= 1) {
      if (tid < s2) red[tid] += red[tid + s2];
      __syncthreads();
    }
    if (tid == 0) out[0] = red[0] / (float)NR;
  }
}

extern "C" void kernel_launch(void* const* d_in, const int* in_sizes, int n_in,
                              void* d_out, int out_size, void* d_ws, size_t ws_size,
                              hipStream_t stream) {
  const float* x  = (const float*)d_in[0];
  const int* tgt  = (const int*)d_in[1];
  float* out      = (float*)d_out;

  unsigned short* xhi = (unsigned short*)d_ws;
  unsigned short* xlo = xhi + (size_t)NR * DIMK;
  float* gP = (float*)((char*)d_ws + (size_t)NR * DIMK * 4);
  float* gN = gP + NR;
  int* counter = (int*)(gN + NR);

  normalize_split_kernel<<<NR / 4, 256, 0, stream>>>(x, xhi, xlo, gP, gN, counter);
  simloss_kernel<<<NBLKS, 512, 0, stream>>>(xhi, xlo, tgt, gP, gN, counter, out);
}